// Round 10
// baseline (55.105 us; speedup 1.0000x reference)
//
#include <hip/hip_runtime.h>
#include <hip/hip_fp16.h>
#include <math.h>

// SSIM loss via MFMA: both separable blurs are banded-matrix GEMMs on the
// matrix pipe (f16 in, f32 accum). Per 64x32 tile:
//   phase1 : load x,y; stage ONLY {x,y} as f16 RAW[48][104] (2 planes)
//   phase2a: wave 0 drains x, wave 1 drains y; waves 2,3 drain BOTH and
//            build s=x^2+y^2 / p=x*y fragments in-register (packed f16)
//   phase2b: H-blur OUTH = RAW(48x96) * Wh(96x64); OUTH aliased at LDS base
//   phase3 : V-blur OUT = Wv(32x64) * OUTH(64x64); SSIM -> per-thread lsum
//   single reduction after the 4-tile loop. 1536 blocks = 6/CU, 4 resident.
// Wh[d][c] = g[d-c-3] (0<=d-c-3<=10), Wv[i][r] = g[r-i] (0<=r-i<=10),
// g[i] = A * 2^(-B*(i-5)^2) regenerated per-lane; zero-pad via zero weights.
// Aliasing safety (validated r8): every LDS byte is zero-init or finite-f16
// forever after; all garbage-capable pad elements meet provably-zero weights
// (cols 80-95: d-c-3>=14; k-rows 42-63: r-16mt-cl>=11), finite*0 = 0.

#define HH 512
#define WW 512
#define NPLANES 48
#define G_TILES 4
#define NBLOCKS 1536           // 6144 tiles / 4

typedef _Float16 f16x8 __attribute__((ext_vector_type(8)));
typedef _Float16 f16x4 __attribute__((ext_vector_type(4)));
typedef float f32x4 __attribute__((ext_vector_type(4)));

#define RAW_STRIDE 208         // bytes per RAW row (104 f16)
#define RAW_PLANE  9984        // 48*208 (x at 0, y at RAW_PLANE)
#define OUTH_CSTR  144         // bytes per OUTH col (72 f16)
#define OUTH_PLANE 9216        // 64*144
#define LDS_TOTAL  36864       // 4*OUTH_PLANE; RAW (2*9984) aliased inside

struct WParam { float A, B; };

__global__ void ssim_init_out(float* out) { out[0] = 1.0f; }

__global__ __launch_bounds__(256, 4)
void ssim_mfma(const float* __restrict__ img, const float* __restrict__ tgt,
               float* __restrict__ out, WParam wp) {
    __shared__ alignas(16) char lds[LDS_TOTAL];
    __shared__ float wsum[4];

    const int tid  = threadIdx.x;
    const int wid  = tid >> 6;
    const int lane = tid & 63;
    const int cl   = lane & 15;
    const int am   = lane >> 4;

    // ---- one-time LDS zero-init (finite-everywhere invariant) ----
    for (int i = tid; i < LDS_TOTAL / 4; i += 256)
        ((float*)lds)[i] = 0.f;

    // ---- one-time per-lane weight fragments ----
    f16x8 Bh[4][3];                       // H-blur B operand [nt][kt]
    #pragma unroll
    for (int nt = 0; nt < 4; ++nt) {
        #pragma unroll
        for (int kt = 0; kt < 3; ++kt) {
            f16x8 f;
            #pragma unroll
            for (int j = 0; j < 8; ++j) {
                int d   = 32*kt + 8*am + j;
                int idx = d - (16*nt + cl) - 3;
                float t = (float)(idx - 5);
                float v = wp.A * exp2f(-wp.B * t * t);
                f[j] = ((unsigned)idx <= 10u) ? (_Float16)v : (_Float16)0.f;
            }
            Bh[nt][kt] = f;
        }
    }
    f16x8 Av[2][2];                       // V-blur A operand [mt][kt]
    #pragma unroll
    for (int mt = 0; mt < 2; ++mt) {
        #pragma unroll
        for (int kt = 0; kt < 2; ++kt) {
            f16x8 f;
            #pragma unroll
            for (int j = 0; j < 8; ++j) {
                int r   = 32*kt + 8*am + j;
                int idx = r - (16*mt + cl);
                float t = (float)(idx - 5);
                float v = wp.A * exp2f(-wp.B * t * t);
                f[j] = ((unsigned)idx <= 10u) ? (_Float16)v : (_Float16)0.f;
            }
            Av[mt][kt] = f;
        }
    }
    __syncthreads();

    const float C1 = 1e-4f, C2 = 9e-4f;
    float lsum = 0.f;

    for (int g = 0; g < G_TILES; ++g) {
        const int tlin = blockIdx.x * G_TILES + g;
        const int p    = tlin >> 7;            // 128 tiles per plane
        const int rem  = tlin & 127;
        const int R0   = (rem >> 3) * 32;
        const int C0   = (rem & 7) * 64;
        const float* ip = img + (size_t)p * (HH * WW);
        const float* tp = tgt + (size_t)p * (HH * WW);

        // ---- phase 1: stage {x, y} as f16 (2 planes) ----
        for (int it = tid; it < 420; it += 256) {
            int r   = it / 10;
            int grp = it - r * 10;
            int gr  = R0 - 5 + r;
            int gc0 = C0 - 8 + grp * 8;
            float4 xa = make_float4(0.f,0.f,0.f,0.f), xb = xa, ya = xa, yb = xa;
            if ((unsigned)gr < (unsigned)HH) {
                const float* xr = ip + (size_t)gr * WW;
                const float* yr = tp + (size_t)gr * WW;
                if ((unsigned)gc0 <= (unsigned)(WW - 4)) {
                    xa = *(const float4*)(xr + gc0);
                    ya = *(const float4*)(yr + gc0);
                }
                if ((unsigned)(gc0 + 4) <= (unsigned)(WW - 4)) {
                    xb = *(const float4*)(xr + gc0 + 4);
                    yb = *(const float4*)(yr + gc0 + 4);
                }
            }
            float fx[8] = {xa.x,xa.y,xa.z,xa.w, xb.x,xb.y,xb.z,xb.w};
            float fy[8] = {ya.x,ya.y,ya.z,ya.w, yb.x,yb.y,yb.z,yb.w};
            f16x8 hx, hy;
            #pragma unroll
            for (int j = 0; j < 8; ++j) {
                hx[j] = (_Float16)fx[j];
                hy[j] = (_Float16)fy[j];
            }
            char* base = lds + r * RAW_STRIDE + grp * 16;
            *(f16x8*)(base + 0*RAW_PLANE) = hx;
            *(f16x8*)(base + 1*RAW_PLANE) = hy;
        }
        __syncthreads();

        // ---- phase 2a: build A fragments (waves 2,3 derive s,p in-reg) ----
        f16x8 Af[3][3];
        {
            const int aoff = cl * RAW_STRIDE + am * 16;
            if (wid < 2) {
                const char* rawq = lds + wid * RAW_PLANE + aoff;
                #pragma unroll
                for (int mt = 0; mt < 3; ++mt)
                    #pragma unroll
                    for (int kt = 0; kt < 3; ++kt)
                        Af[mt][kt] = *(const f16x8*)(rawq + mt*3328 + kt*64);
            } else {
                const char* rx = lds + aoff;
                const char* ry = lds + RAW_PLANE + aoff;
                #pragma unroll
                for (int mt = 0; mt < 3; ++mt) {
                    #pragma unroll
                    for (int kt = 0; kt < 3; ++kt) {
                        f16x8 ax = *(const f16x8*)(rx + mt*3328 + kt*64);
                        f16x8 ay = *(const f16x8*)(ry + mt*3328 + kt*64);
                        Af[mt][kt] = (wid == 2) ? (f16x8)(ax*ax + ay*ay)
                                                : (f16x8)(ax*ay);
                    }
                }
            }
        }
        __syncthreads();   // RAW fully drained before OUTH overwrites it

        // ---- phase 2b: H-blur MFMA, write OUTH (aliased at LDS base) ----
        {
            char* outq = lds + wid * OUTH_PLANE;
            const int woff = cl * OUTH_CSTR + am * 8;
            #pragma unroll
            for (int nt = 0; nt < 4; ++nt) {
                #pragma unroll
                for (int mt = 0; mt < 3; ++mt) {
                    f32x4 acc = {0.f, 0.f, 0.f, 0.f};
                    #pragma unroll
                    for (int kt = 0; kt < 3; ++kt)
                        acc = __builtin_amdgcn_mfma_f32_16x16x32_f16(
                                  Af[mt][kt], Bh[nt][kt], acc, 0, 0, 0);
                    f16x4 h;
                    #pragma unroll
                    for (int j = 0; j < 4; ++j) h[j] = (_Float16)acc[j];
                    *(f16x4*)(outq + woff + nt*2304 + mt*32) = h;
                }
            }
        }
        __syncthreads();

        // ---- phase 3: V-blur (wave wid handles cols 16*wid..16*wid+15) ----
        {
            const int boff = (16*wid + cl) * OUTH_CSTR + am * 16;
            f32x4 accv[4][2];
            #pragma unroll
            for (int q = 0; q < 4; ++q) {
                f16x8 Bf0 = *(const f16x8*)(lds + q*OUTH_PLANE + boff);
                f16x8 Bf1 = *(const f16x8*)(lds + q*OUTH_PLANE + boff + 64);
                #pragma unroll
                for (int mt = 0; mt < 2; ++mt) {
                    f32x4 acc = {0.f, 0.f, 0.f, 0.f};
                    acc = __builtin_amdgcn_mfma_f32_16x16x32_f16(Av[mt][0], Bf0, acc, 0, 0, 0);
                    acc = __builtin_amdgcn_mfma_f32_16x16x32_f16(Av[mt][1], Bf1, acc, 0, 0, 0);
                    accv[q][mt] = acc;
                }
            }
            #pragma unroll
            for (int mt = 0; mt < 2; ++mt) {
                #pragma unroll
                for (int j = 0; j < 4; ++j) {
                    float mu1 = accv[0][mt][j], mu2 = accv[1][mt][j];
                    float bss = accv[2][mt][j], bxy = accv[3][mt][j];
                    float mu1s = mu1*mu1, mu2s = mu2*mu2, mu12 = mu1*mu2;
                    float ssum = bss - mu1s - mu2s;
                    float s12  = bxy - mu12;
                    float num = (2.f*mu12 + C1) * (2.f*s12 + C2);
                    float den = (mu1s + mu2s + C1) * (ssum + C2);
                    lsum = fmaf(num, __builtin_amdgcn_rcpf(den), lsum);
                }
            }
        }
        __syncthreads();   // OUTH fully read before next phase-1 overwrites
    }

    // ---- single block reduction + one atomic ----
    for (int off = 32; off > 0; off >>= 1)
        lsum += __shfl_down(lsum, off, 64);
    if (lane == 0) wsum[wid] = lsum;
    __syncthreads();
    if (tid == 0) {
        float bsum = wsum[0] + wsum[1] + wsum[2] + wsum[3];
        const float invN = 1.0f / (float)((size_t)NPLANES * HH * WW);
        atomicAdd(out, -bsum * invN);
    }
}

extern "C" void kernel_launch(void* const* d_in, const int* in_sizes, int n_in,
                              void* d_out, int out_size, void* d_ws, size_t ws_size,
                              hipStream_t stream) {
    const float* img = (const float*)d_in[0];
    const float* tgt = (const float*)d_in[1];
    float* out = (float*)d_out;

    // g[i] = exp(-(i-5)^2/4.5)/s = A * 2^(-B*(i-5)^2), A = 1/s, B = log2(e)/4.5
    double s = 0.0;
    for (int i = 0; i < 11; ++i) {
        double d = (double)(i - 5);
        s += exp(-(d * d) / 4.5);
    }
    WParam wp;
    wp.A = (float)(1.0 / s);
    wp.B = (float)(M_LOG2E / 4.5);

    ssim_init_out<<<1, 1, 0, stream>>>(out);
    ssim_mfma<<<NBLOCKS, 256, 0, stream>>>(img, tgt, out, wp);
}

// Round 11
// 45.126 us; speedup vs baseline: 1.2211x; 1.2211x over previous
//
#include <hip/hip_runtime.h>
#include <hip/hip_fp16.h>
#include <math.h>

// SSIM loss via MFMA, K=32 banded GEMMs. Per 64x32 tile:
//   phase1: load x,y; compute {x,y,x2+y2,xy}; stage f16 RAW[48][104] x4 planes
//   phase2: per wave q (plane q): for each 16x16 output block (mt,nt), ONE
//           K=32 MFMA with k-base 16nt (H-blur band is only 26 wide);
//           OUTH-q (col-major, 64 cols x 52-row stride, 6656B = RAW rows 0..31)
//           aliased INSIDE RAW-q -> intra-wave-only hazard, no barrier:
//           read all Af -> sched_barrier(0) -> MFMA -> write (DS in-order/wave)
//   phase3: V-blur: per (q, mt) ONE K=32 MFMA with k-base 16mt; SSIM -> lsum
//   3 barriers/tile. 8 tiles/block, 768 blocks = 3/CU (LDS 39.9KB, 4 fit).
// Weights: single fragment each. Bh[j] = g[8am+j-cl-3], Av[j] = g[8am+j-cl]
// (validated r7/r8 as the [0][0] fragments), g[i] = A*2^(-B*(i-5)^2).
// Zero-pad invariants: RAW rows 42-47 and cols 80-103 outside both the ph1
// write window (rows 0-41, cols 0-79) and the OUTH alias window (rows 0-31);
// Af reads bytes [0,160) only -> stale OUTH bytes [160,208) never read.

#define HH 512
#define WW 512
#define NPLANES 48
#define G_TILES 8
#define NBLOCKS 768            // 6144 tiles / 8

typedef _Float16 f16x8 __attribute__((ext_vector_type(8)));
typedef _Float16 f16x4 __attribute__((ext_vector_type(4)));
typedef float f32x4 __attribute__((ext_vector_type(4)));

#define RAW_STRIDE 208         // bytes per RAW row (104 f16); 52 words
#define RAW_PLANE  9984        // 48*208 per plane; x,y,s,p at q*RAW_PLANE
#define OUTH_CSTR  104         // bytes per OUTH col (52 f16; 48 used)
#define LDS_TOTAL  39936       // 4*RAW_PLANE; OUTH-q aliased inside RAW-q

struct WParam { float A, B; };

__global__ void ssim_init_out(float* out) { out[0] = 1.0f; }

__global__ __launch_bounds__(256, 4)
void ssim_mfma(const float* __restrict__ img, const float* __restrict__ tgt,
               float* __restrict__ out, WParam wp) {
    __shared__ alignas(16) char lds[LDS_TOTAL];
    __shared__ float wsum[4];

    const int tid  = threadIdx.x;
    const int wid  = tid >> 6;
    const int lane = tid & 63;
    const int cl   = lane & 15;
    const int am   = lane >> 4;

    // ---- one-time LDS zero-init (pad-regions-forever-zero invariant) ----
    for (int i = tid; i < LDS_TOTAL / 4; i += 256)
        ((float*)lds)[i] = 0.f;

    // ---- one-time per-lane weight fragments (one each) ----
    f16x8 Bh, Av;
    #pragma unroll
    for (int j = 0; j < 8; ++j) {
        int k = 8 * am + j;
        int ih = k - cl - 3;
        float th = (float)(ih - 5);
        Bh[j] = ((unsigned)ih <= 10u) ? (_Float16)(wp.A * exp2f(-wp.B * th * th))
                                      : (_Float16)0.f;
        int iv = k - cl;
        float tv = (float)(iv - 5);
        Av[j] = ((unsigned)iv <= 10u) ? (_Float16)(wp.A * exp2f(-wp.B * tv * tv))
                                      : (_Float16)0.f;
    }
    __syncthreads();

    const float C1 = 1e-4f, C2 = 9e-4f;
    float lsum = 0.f;

    for (int g = 0; g < G_TILES; ++g) {
        const int tlin = blockIdx.x * G_TILES + g;
        const int p    = tlin >> 7;            // 128 tiles per plane
        const int rem  = tlin & 127;
        const int R0   = (rem >> 3) * 32;
        const int C0   = (rem & 7) * 64;
        const float* ip = img + (size_t)p * (HH * WW);
        const float* tp = tgt + (size_t)p * (HH * WW);

        // ---- phase 1: stage RAW planes {x, y, x2+y2, xy} as f16 ----
        for (int it = tid; it < 420; it += 256) {
            int r   = it / 10;
            int grp = it - r * 10;
            int gr  = R0 - 5 + r;
            int gc0 = C0 - 8 + grp * 8;
            float4 xa = make_float4(0.f,0.f,0.f,0.f), xb = xa, ya = xa, yb = xa;
            if ((unsigned)gr < (unsigned)HH) {
                const float* xr = ip + (size_t)gr * WW;
                const float* yr = tp + (size_t)gr * WW;
                if ((unsigned)gc0 <= (unsigned)(WW - 4)) {
                    xa = *(const float4*)(xr + gc0);
                    ya = *(const float4*)(yr + gc0);
                }
                if ((unsigned)(gc0 + 4) <= (unsigned)(WW - 4)) {
                    xb = *(const float4*)(xr + gc0 + 4);
                    yb = *(const float4*)(yr + gc0 + 4);
                }
            }
            float fx[8] = {xa.x,xa.y,xa.z,xa.w, xb.x,xb.y,xb.z,xb.w};
            float fy[8] = {ya.x,ya.y,ya.z,ya.w, yb.x,yb.y,yb.z,yb.w};
            f16x8 hx, hy, hs, hp;
            #pragma unroll
            for (int j = 0; j < 8; ++j) {
                hx[j] = (_Float16)fx[j];
                hy[j] = (_Float16)fy[j];
                hs[j] = (_Float16)fmaf(fx[j], fx[j], fy[j]*fy[j]);
                hp[j] = (_Float16)(fx[j] * fy[j]);
            }
            char* base = lds + r * RAW_STRIDE + grp * 16;
            *(f16x8*)(base + 0*RAW_PLANE) = hx;
            *(f16x8*)(base + 1*RAW_PLANE) = hy;
            *(f16x8*)(base + 2*RAW_PLANE) = hs;
            *(f16x8*)(base + 3*RAW_PLANE) = hp;
        }
        __syncthreads();

        // ---- phase 2: H-blur, wave q = plane q; OUTH-q aliased in RAW-q ----
        {
            char* plane = lds + wid * RAW_PLANE;
            const int abase = cl * RAW_STRIDE + am * 16;
            f16x8 Af[3][4];
            #pragma unroll
            for (int mt = 0; mt < 3; ++mt)
                #pragma unroll
                for (int nt = 0; nt < 4; ++nt)
                    Af[mt][nt] = *(const f16x8*)(plane + abase
                                                 + mt * 16 * RAW_STRIDE + nt * 32);
            __builtin_amdgcn_sched_barrier(0);   // all reads before any write
            const int wbase = cl * OUTH_CSTR + am * 8;
            #pragma unroll
            for (int nt = 0; nt < 4; ++nt) {
                #pragma unroll
                for (int mt = 0; mt < 3; ++mt) {
                    f32x4 acc = {0.f, 0.f, 0.f, 0.f};
                    acc = __builtin_amdgcn_mfma_f32_16x16x32_f16(
                              Af[mt][nt], Bh, acc, 0, 0, 0);
                    f16x4 h;
                    #pragma unroll
                    for (int j = 0; j < 4; ++j) h[j] = (_Float16)acc[j];
                    *(f16x4*)(plane + wbase + nt * 16 * OUTH_CSTR + mt * 32) = h;
                }
            }
        }
        __syncthreads();

        // ---- phase 3: V-blur (wave wid = cols 16*wid..16*wid+15) + SSIM ----
        {
            const int bbase = (16 * wid + cl) * OUTH_CSTR + am * 16;
            f32x4 accv[4][2];
            #pragma unroll
            for (int q = 0; q < 4; ++q) {
                #pragma unroll
                for (int mt = 0; mt < 2; ++mt) {
                    f16x8 Bf = *(const f16x8*)(lds + q * RAW_PLANE + bbase + mt * 32);
                    f32x4 acc = {0.f, 0.f, 0.f, 0.f};
                    accv[q][mt] = __builtin_amdgcn_mfma_f32_16x16x32_f16(
                                      Av, Bf, acc, 0, 0, 0);
                }
            }
            #pragma unroll
            for (int mt = 0; mt < 2; ++mt) {
                #pragma unroll
                for (int j = 0; j < 4; ++j) {
                    float mu1 = accv[0][mt][j], mu2 = accv[1][mt][j];
                    float bss = accv[2][mt][j], bxy = accv[3][mt][j];
                    float mu1s = mu1*mu1, mu2s = mu2*mu2, mu12 = mu1*mu2;
                    float ssum = bss - mu1s - mu2s;
                    float s12  = bxy - mu12;
                    float num = (2.f*mu12 + C1) * (2.f*s12 + C2);
                    float den = (mu1s + mu2s + C1) * (ssum + C2);
                    lsum = fmaf(num, __builtin_amdgcn_rcpf(den), lsum);
                }
            }
        }
        __syncthreads();   // OUTH/RAW fully read before next phase-1 overwrites
    }

    // ---- single block reduction + one atomic ----
    for (int off = 32; off > 0; off >>= 1)
        lsum += __shfl_down(lsum, off, 64);
    if (lane == 0) wsum[wid] = lsum;
    __syncthreads();
    if (tid == 0) {
        float bsum = wsum[0] + wsum[1] + wsum[2] + wsum[3];
        const float invN = 1.0f / (float)((size_t)NPLANES * HH * WW);
        atomicAdd(out, -bsum * invN);
    }
}

extern "C" void kernel_launch(void* const* d_in, const int* in_sizes, int n_in,
                              void* d_out, int out_size, void* d_ws, size_t ws_size,
                              hipStream_t stream) {
    const float* img = (const float*)d_in[0];
    const float* tgt = (const float*)d_in[1];
    float* out = (float*)d_out;

    // g[i] = exp(-(i-5)^2/4.5)/s = A * 2^(-B*(i-5)^2), A = 1/s, B = log2(e)/4.5
    double s = 0.0;
    for (int i = 0; i < 11; ++i) {
        double d = (double)(i - 5);
        s += exp(-(d * d) / 4.5);
    }
    WParam wp;
    wp.A = (float)(1.0 / s);
    wp.B = (float)(M_LOG2E / 4.5);

    ssim_init_out<<<1, 1, 0, stream>>>(out);
    ssim_mfma<<<NBLOCKS, 256, 0, stream>>>(img, tgt, out, wp);
}

// Round 12
// 40.725 us; speedup vs baseline: 1.3531x; 1.1081x over previous
//
#include <hip/hip_runtime.h>
#include <hip/hip_fp16.h>
#include <math.h>

// SSIM loss via MFMA, K=32 banded GEMMs + cross-tile register prefetch.
// Per 64x32 tile:
//   ph1: write prefetched {x,y} regs as f16 planes {x,y,x2+y2,xy} (packed-f16
//        products); then ISSUE next tile's global loads (stay in flight
//        across raw s_barriers - no vmcnt drain, unlike __syncthreads).
//   ph2: H-blur, wave q = plane q, ONE K=32 MFMA per 16x16 block (banded);
//        OUTH-q aliased inside RAW-q (intra-wave hazard only: reads ->
//        sched_barrier(0) -> MFMA -> writes; DS in-order per wave).
//   ph3: V-blur ONE K=32 MFMA per (q,mt); SSIM -> per-thread lsum.
// Raw-barrier protocol: s_waitcnt lgkmcnt(0) + s_barrier + sched_barrier(0)
// (only DS ops need cross-wave ordering; global loads are thread-private).
// Weights: Bh[j]=g[8am+j-cl-3], Av[j]=g[8am+j-cl] (validated r7/r8/r11),
// g[i]=A*2^(-B*(i-5)^2). Zero-pad via zero weights over zero-init'd LDS
// (finite*0=0 invariant, validated r7-r11).

#define HH 512
#define WW 512
#define NPLANES 48
#define G_TILES 8
#define NBLOCKS 768            // 6144 tiles / 8

typedef _Float16 f16x8 __attribute__((ext_vector_type(8)));
typedef _Float16 f16x4 __attribute__((ext_vector_type(4)));
typedef float f32x4 __attribute__((ext_vector_type(4)));

#define RAW_STRIDE 208         // bytes per RAW row (104 f16); 52 words
#define RAW_PLANE  9984        // 48*208 per plane; planes at q*RAW_PLANE
#define OUTH_CSTR  104         // bytes per OUTH col (52 f16; 48 used)
#define LDS_TOTAL  39936       // 4*RAW_PLANE; OUTH-q aliased inside RAW-q

struct WParam { float A, B; };

__global__ void ssim_init_out(float* out) { out[0] = 1.0f; }

__device__ __forceinline__ void barrier_nodrain() {
    asm volatile("s_waitcnt lgkmcnt(0)" ::: "memory");
    __builtin_amdgcn_s_barrier();
    __builtin_amdgcn_sched_barrier(0);
}

__global__ __launch_bounds__(256, 4)
void ssim_mfma(const float* __restrict__ img, const float* __restrict__ tgt,
               float* __restrict__ out, WParam wp) {
    __shared__ alignas(16) char lds[LDS_TOTAL];
    __shared__ float wsum[4];

    const int tid  = threadIdx.x;
    const int wid  = tid >> 6;
    const int lane = tid & 63;
    const int cl   = lane & 15;
    const int am   = lane >> 4;

    // fixed 2 staging items per thread (420 = 256 + 164)
    const int it0 = tid,       ir0 = it0 / 10, ig0 = it0 - 10 * ir0;
    const int it1 = tid + 256, ir1 = it1 / 10, ig1 = it1 - 10 * ir1;
    const bool has1 = (tid < 164);

    float4 Xa[2], Xb[2], Ya[2], Yb[2];

    auto load_tile = [&](int tlin) {
        const int p   = tlin >> 7;
        const int rem = tlin & 127;
        const int R0  = (rem >> 3) * 32;
        const int C0  = (rem & 7) * 64;
        const float* ip = img + (size_t)p * (HH * WW);
        const float* tp = tgt + (size_t)p * (HH * WW);
        #pragma unroll
        for (int s = 0; s < 2; ++s) {
            if (s == 1 && !has1) break;
            int r   = s ? ir1 : ir0;
            int grp = s ? ig1 : ig0;
            int gr  = R0 - 5 + r;
            int gc0 = C0 - 8 + grp * 8;
            float4 xa = make_float4(0.f,0.f,0.f,0.f), xb = xa, ya = xa, yb = xa;
            if ((unsigned)gr < (unsigned)HH) {
                const float* xr = ip + (size_t)gr * WW;
                const float* yr = tp + (size_t)gr * WW;
                if ((unsigned)gc0 <= (unsigned)(WW - 4)) {
                    xa = *(const float4*)(xr + gc0);
                    ya = *(const float4*)(yr + gc0);
                }
                if ((unsigned)(gc0 + 4) <= (unsigned)(WW - 4)) {
                    xb = *(const float4*)(xr + gc0 + 4);
                    yb = *(const float4*)(yr + gc0 + 4);
                }
            }
            Xa[s] = xa; Xb[s] = xb; Ya[s] = ya; Yb[s] = yb;
        }
    };

    auto write_tile = [&]() {
        #pragma unroll
        for (int s = 0; s < 2; ++s) {
            if (s == 1 && !has1) break;
            int r   = s ? ir1 : ir0;
            int grp = s ? ig1 : ig0;
            float fx[8] = {Xa[s].x,Xa[s].y,Xa[s].z,Xa[s].w,
                           Xb[s].x,Xb[s].y,Xb[s].z,Xb[s].w};
            float fy[8] = {Ya[s].x,Ya[s].y,Ya[s].z,Ya[s].w,
                           Yb[s].x,Yb[s].y,Yb[s].z,Yb[s].w};
            f16x8 hx, hy;
            #pragma unroll
            for (int j = 0; j < 8; ++j) {
                hx[j] = (_Float16)fx[j];
                hy[j] = (_Float16)fy[j];
            }
            f16x8 hs = hx*hx + hy*hy;     // v_pk_mul/fma_f16
            f16x8 hp = hx*hy;
            char* base = lds + r * RAW_STRIDE + grp * 16;
            *(f16x8*)(base + 0*RAW_PLANE) = hx;
            *(f16x8*)(base + 1*RAW_PLANE) = hy;
            *(f16x8*)(base + 2*RAW_PLANE) = hs;
            *(f16x8*)(base + 3*RAW_PLANE) = hp;
        }
    };

    const int base_t = blockIdx.x * G_TILES;
    load_tile(base_t);                 // prologue prefetch (overlaps init)

    // ---- one-time LDS zero-init (pad-regions-forever-zero invariant) ----
    for (int i = tid; i < LDS_TOTAL / 4; i += 256)
        ((float*)lds)[i] = 0.f;

    // ---- one-time per-lane weight fragments ----
    f16x8 Bh, Av;
    #pragma unroll
    for (int j = 0; j < 8; ++j) {
        int k = 8 * am + j;
        int ih = k - cl - 3;
        float th = (float)(ih - 5);
        Bh[j] = ((unsigned)ih <= 10u) ? (_Float16)(wp.A * exp2f(-wp.B * th * th))
                                      : (_Float16)0.f;
        int iv = k - cl;
        float tv = (float)(iv - 5);
        Av[j] = ((unsigned)iv <= 10u) ? (_Float16)(wp.A * exp2f(-wp.B * tv * tv))
                                      : (_Float16)0.f;
    }
    __syncthreads();

    const float C1 = 1e-4f, C2 = 9e-4f;
    float lsum = 0.f;

    for (int g = 0; g < G_TILES; ++g) {
        // ---- phase 1: write prefetched tile to LDS; issue next prefetch ----
        write_tile();
        if (g + 1 < G_TILES) load_tile(base_t + g + 1);
        barrier_nodrain();

        // ---- phase 2: H-blur, wave q = plane q; OUTH-q aliased in RAW-q ----
        {
            char* plane = lds + wid * RAW_PLANE;
            const int abase = cl * RAW_STRIDE + am * 16;
            f16x8 Af[3][4];
            #pragma unroll
            for (int mt = 0; mt < 3; ++mt)
                #pragma unroll
                for (int nt = 0; nt < 4; ++nt)
                    Af[mt][nt] = *(const f16x8*)(plane + abase
                                                 + mt * 16 * RAW_STRIDE + nt * 32);
            __builtin_amdgcn_sched_barrier(0);   // all reads before any write
            const int wbase = cl * OUTH_CSTR + am * 8;
            #pragma unroll
            for (int nt = 0; nt < 4; ++nt) {
                #pragma unroll
                for (int mt = 0; mt < 3; ++mt) {
                    f32x4 acc = {0.f, 0.f, 0.f, 0.f};
                    acc = __builtin_amdgcn_mfma_f32_16x16x32_f16(
                              Af[mt][nt], Bh, acc, 0, 0, 0);
                    f16x4 h;
                    #pragma unroll
                    for (int j = 0; j < 4; ++j) h[j] = (_Float16)acc[j];
                    *(f16x4*)(plane + wbase + nt * 16 * OUTH_CSTR + mt * 32) = h;
                }
            }
        }
        barrier_nodrain();

        // ---- phase 3: V-blur (wave wid = cols 16*wid..16*wid+15) + SSIM ----
        {
            const int bbase = (16 * wid + cl) * OUTH_CSTR + am * 16;
            f32x4 accv[4][2];
            #pragma unroll
            for (int q = 0; q < 4; ++q) {
                #pragma unroll
                for (int mt = 0; mt < 2; ++mt) {
                    f16x8 Bf = *(const f16x8*)(lds + q * RAW_PLANE + bbase + mt * 32);
                    f32x4 acc = {0.f, 0.f, 0.f, 0.f};
                    accv[q][mt] = __builtin_amdgcn_mfma_f32_16x16x32_f16(
                                      Av, Bf, acc, 0, 0, 0);
                }
            }
            #pragma unroll
            for (int mt = 0; mt < 2; ++mt) {
                #pragma unroll
                for (int j = 0; j < 4; ++j) {
                    float mu1 = accv[0][mt][j], mu2 = accv[1][mt][j];
                    float bss = accv[2][mt][j], bxy = accv[3][mt][j];
                    float mu1s = mu1*mu1, mu2s = mu2*mu2, mu12 = mu1*mu2;
                    float ssum = bss - mu1s - mu2s;
                    float s12  = bxy - mu12;
                    float num = (2.f*mu12 + C1) * (2.f*s12 + C2);
                    float den = (mu1s + mu2s + C1) * (ssum + C2);
                    lsum = fmaf(num, __builtin_amdgcn_rcpf(den), lsum);
                }
            }
        }
        barrier_nodrain();   // all OUTH/RAW reads done before next ph1 write
    }

    // ---- single block reduction + one atomic ----
    for (int off = 32; off > 0; off >>= 1)
        lsum += __shfl_down(lsum, off, 64);
    if (lane == 0) wsum[wid] = lsum;
    __syncthreads();
    if (tid == 0) {
        float bsum = wsum[0] + wsum[1] + wsum[2] + wsum[3];
        const float invN = 1.0f / (float)((size_t)NPLANES * HH * WW);
        atomicAdd(out, -bsum * invN);
    }
}

extern "C" void kernel_launch(void* const* d_in, const int* in_sizes, int n_in,
                              void* d_out, int out_size, void* d_ws, size_t ws_size,
                              hipStream_t stream) {
    const float* img = (const float*)d_in[0];
    const float* tgt = (const float*)d_in[1];
    float* out = (float*)d_out;

    // g[i] = exp(-(i-5)^2/4.5)/s = A * 2^(-B*(i-5)^2), A = 1/s, B = log2(e)/4.5
    double s = 0.0;
    for (int i = 0; i < 11; ++i) {
        double d = (double)(i - 5);
        s += exp(-(d * d) / 4.5);
    }
    WParam wp;
    wp.A = (float)(1.0 / s);
    wp.B = (float)(M_LOG2E / 4.5);

    ssim_init_out<<<1, 1, 0, stream>>>(out);
    ssim_mfma<<<NBLOCKS, 256, 0, stream>>>(img, tgt, out, wp);
}